// Round 12
// baseline (262.436 us; speedup 1.0000x reference)
//
#include <hip/hip_runtime.h>
#include <hip/hip_bf16.h>

#define N_NODES 100000
#define N_EDGES 1600000
#define HID 64
#define OUT_CH 32

// Deterministic radix partition into dst buckets. Zero global atomics for
// cursors (R5). R1/R2: channel-chunked gather loses (request-rate bound).
// R3: pre-swizzle weights once. R5: head fused into layer3. R6: gather
// MLP-deepening (16 int4 in flight/lane, lane-owned channels) -36 us.
// R7: software grid barriers cost ~100us on MI355X -> never fuse that way.
// R8: block-local gather+layer fusion (agg stays in LDS) -15 us.
// R9: clamp-to-row-0 batched loads beat exec-mask predication on CDNA4.
// R11: place in-LDS counting sort (coalesced bkt writes) -6 us.
// This round: weight fragments read directly from L2-hot global wpk
// (LDS 43.5K -> 18.7K => 3 -> 4 blocks/CU, +33% waves for the
// latency-bound gather).
#define NB 196           // ceil(100000/512) buckets of 512 consecutive dst nodes
#define P 1024           // partition blocks
#define EPP ((N_EDGES + P - 1) / P)   // 1563 edges per block
#define BKCAP 10240      // LDS csr staging cap (bucket mean 8192, sigma ~90)
#define MP 72            // bf16 tile pitch for MFMA layer (16B-aligned rows)

typedef unsigned short ushort_t;
typedef short bf16x8 __attribute__((ext_vector_type(8)));
typedef float f32x4 __attribute__((ext_vector_type(4)));

// bf16 helpers (RNE)
__device__ __forceinline__ ushort_t f2b(float f) {
    union { float f; unsigned u; } un; un.f = f;
    unsigned r = un.u + 0x7FFF + ((un.u >> 16) & 1);
    return (ushort_t)(r >> 16);
}
__device__ __forceinline__ float blo(unsigned u) {
    union { unsigned u; float f; } un; un.u = u << 16; return un.f;
}
__device__ __forceinline__ float bhi(unsigned u) {
    union { unsigned u; float f; } un; un.u = u & 0xFFFF0000u; return un.f;
}

__device__ __forceinline__ int get_dst(const int* __restrict__ ei, int is64, int e) {
    return is64 ? ((const int2*)ei)[N_EDGES + e].x : ei[N_EDGES + e];
}
__device__ __forceinline__ int get_src(const int* __restrict__ ei, int is64, int e) {
    return is64 ? ((const int2*)ei)[e].x : ei[e];
}

// inline edge-dtype probe: int64 => odd 32-bit words all 0 (first wave)
__device__ __forceinline__ void detect_is64(const int* __restrict__ ei,
                                            int* __restrict__ sflag, int tid) {
    if (tid < 64) {
        int v = ei[2 * tid + 1];
        unsigned long long ball = __ballot(v == 0);
        if (tid == 0) *sflag = (ball == ~0ull) ? 1 : 0;
    }
}

// ---- convert x -> bf16 + bucket histograms (blocks <P) + weight swizzle ---
#define CONV_BLOCKS ((N_NODES * HID / 4) / 256)   // 6250
__global__ void __launch_bounds__(256) convhist_kernel(
        const float* __restrict__ x, ushort_t* __restrict__ xb,
        const int* __restrict__ ei, int* __restrict__ histG,
        const float* __restrict__ W0, const float* __restrict__ W1,
        const float* __restrict__ W2, const float* __restrict__ W3,
        const float* __restrict__ W4, const float* __restrict__ W5,
        ushort_t* __restrict__ wpk) {
    int bid = blockIdx.x;
    if (bid >= CONV_BLOCKS) {        // weight-swizzle blocks
        const float* Ws[6] = {W0, W1, W2, W3, W4, W5};
        int w = bid - CONV_BLOCKS;
        const float* W = Ws[w];
        ushort_t* d = wpk + w * 4096;
        for (int idx = threadIdx.x; idx < 4096; idx += 256) {
            int j = idx & 7;
            int ln = (idx >> 3) & 63;
            int t = idx >> 9;            // nt*2+ks
            int ks = t & 1, nt = t >> 1;
            int k = ks * 32 + (ln >> 4) * 8 + j;
            int n = nt * 16 + (ln & 15);
            d[idx] = f2b(W[k * HID + n]);
        }
        return;
    }
    int i = bid * 256 + threadIdx.x;
    if (i < N_NODES * HID / 4) {
        float4 v = ((const float4*)x)[i];
        ushort4 o;
        o.x = f2b(v.x); o.y = f2b(v.y); o.z = f2b(v.z); o.w = f2b(v.w);
        ((ushort4*)xb)[i] = o;
    }
    if (bid >= P) return;
    __shared__ int sflag;
    __shared__ int lh[NB];
    int tid = threadIdx.x;
    detect_is64(ei, &sflag, tid);
    for (int k = tid; k < NB; k += 256) lh[k] = 0;
    __syncthreads();
    int is64 = sflag;
    int e0 = bid * EPP;
    int e1 = min(e0 + EPP, N_EDGES);
    for (int e = e0 + tid; e < e1; e += 256) {
        int d = get_dst(ei, is64, e);
        atomicAdd(&lh[d >> 9], 1);
    }
    __syncthreads();
    for (int k = tid; k < NB; k += 256) histG[k * P + bid] = lh[k];
}

// ---- per-bucket exclusive scan over P block-counts (4 elems/thread) -------
__global__ void __launch_bounds__(256) scan_kernel(int* __restrict__ histG,
                                                   int* __restrict__ btot) {
    __shared__ int ps[256];
    int b = blockIdx.x;
    int tid = threadIdx.x;
    int base4 = b * P + 4 * tid;
    int v0 = histG[base4], v1 = histG[base4 + 1], v2 = histG[base4 + 2], v3 = histG[base4 + 3];
    int pv = v0 + v1 + v2 + v3;
    ps[tid] = pv;
    __syncthreads();
    for (int d = 1; d < 256; d <<= 1) {
        int t = (tid >= d) ? ps[tid - d] : 0;
        __syncthreads();
        ps[tid] += t;
        __syncthreads();
    }
    int e = ps[tid] - pv;
    histG[base4] = e; e += v0;
    histG[base4 + 1] = e; e += v1;
    histG[base4 + 2] = e; e += v2;
    histG[base4 + 3] = e;
    if (tid == 255) btot[b] = ps[255];
}

// ---- place v2: in-LDS counting sort, coalesced bkt writes -----------------
__global__ void __launch_bounds__(256) place_kernel(
        const int* __restrict__ ei, const int* __restrict__ histG,
        const int* __restrict__ btot, int* __restrict__ bkt) {
    __shared__ int ss[256];
    __shared__ int sflag;
    __shared__ int gb0[NB];      // bucket global base + my scanned offset
    __shared__ int lcnt[NB];
    __shared__ int lrun[256];    // scan workspace
    __shared__ int gbase[NB];    // gb0[k] - excl[k]
    __shared__ int lcur[NB];
    __shared__ int valbuf[EPP];
    __shared__ unsigned char kbuf[EPP];
    __shared__ int sortv[EPP];
    __shared__ int sorta[EPP];
    int tid = threadIdx.x;
    detect_is64(ei, &sflag, tid);
    int v = (tid < NB) ? btot[tid] : 0;
    ss[tid] = v;
    __syncthreads();
    for (int d = 1; d < 256; d <<= 1) {
        int t = (tid >= d) ? ss[tid - d] : 0;
        __syncthreads();
        ss[tid] += t;
        __syncthreads();
    }
    if (tid < NB) gb0[tid] = (ss[tid] - v) + histG[tid * P + blockIdx.x];
    for (int k = tid; k < NB; k += 256) lcnt[k] = 0;
    __syncthreads();
    int is64 = sflag;
    int e0 = blockIdx.x * EPP;
    int e1 = min(e0 + EPP, N_EDGES);
    int m = e1 - e0;
    for (int i = tid; i < m; i += 256) {
        int e = e0 + i;
        int s = get_src(ei, is64, e);
        int d = get_dst(ei, is64, e);
        valbuf[i] = ((d & 511) << 17) | s;
        int k = d >> 9;
        kbuf[i] = (unsigned char)k;
        atomicAdd(&lcnt[k], 1);
    }
    __syncthreads();
    int c = (tid < NB) ? lcnt[tid] : 0;
    lrun[tid] = c;
    __syncthreads();
    for (int d = 1; d < 256; d <<= 1) {
        int t = (tid >= d) ? lrun[tid - d] : 0;
        __syncthreads();
        lrun[tid] += t;
        __syncthreads();
    }
    if (tid < NB) {
        int excl = lrun[tid] - c;
        gbase[tid] = gb0[tid] - excl;
        lcur[tid] = excl;
    }
    __syncthreads();
    for (int i = tid; i < m; i += 256) {
        int k = kbuf[i];
        int p = atomicAdd(&lcur[k], 1);
        sortv[p] = valbuf[i];
        sorta[p] = gbase[k];
    }
    __syncthreads();
    for (int i = tid; i < m; i += 256)
        bkt[sorta[i] + i] = sortv[i];
}

// ---- per-bucket csr build in LDS + packed off|deg -------------------------
__global__ void __launch_bounds__(256) bucket_fill_kernel(
        const int* __restrict__ btot, const int* __restrict__ bkt,
        int* __restrict__ csr, unsigned int* __restrict__ offpk) {
    __shared__ int lcnt[512];
    __shared__ int loff[512];
    __shared__ int lcur[512];
    __shared__ int ps[256];
    __shared__ int scsr[BKCAP];
    __shared__ int sbase;
    int b = blockIdx.x;
    int tid = threadIdx.x;
    int m = btot[b];
    int vb = (tid < NB) ? btot[tid] : 0;
    ps[tid] = vb;
    __syncthreads();
    for (int d = 1; d < 256; d <<= 1) {
        int t = (tid >= d) ? ps[tid - d] : 0;
        __syncthreads();
        ps[tid] += t;
        __syncthreads();
    }
    if (tid == b) sbase = ps[tid] - vb;   // exclusive prefix at b
    __syncthreads();
    int base = sbase;
    int n0 = b << 9;
    int nn = min(512, N_NODES - n0);

    lcnt[tid] = 0;
    lcnt[tid + 256] = 0;
    __syncthreads();
    for (int i = tid; i < m; i += 256) atomicAdd(&lcnt[bkt[base + i] >> 17], 1);
    __syncthreads();
    int a0 = lcnt[2 * tid], a1 = lcnt[2 * tid + 1];
    int pv = a0 + a1;
    ps[tid] = pv;
    __syncthreads();
    for (int d = 1; d < 256; d <<= 1) {
        int t = (tid >= d) ? ps[tid - d] : 0;
        __syncthreads();
        ps[tid] += t;
        __syncthreads();
    }
    int excl = ps[tid] - pv;
    loff[2 * tid] = excl;
    loff[2 * tid + 1] = excl + a0;
    lcur[2 * tid] = excl;
    lcur[2 * tid + 1] = excl + a0;
    __syncthreads();
    bool fit = (m <= BKCAP);
    for (int i = tid; i < m; i += 256) {
        int val = bkt[base + i];
        int dl = val >> 17;
        int p = atomicAdd(&lcur[dl], 1);
        if (fit) scsr[p] = val & 0x1FFFF;
        else csr[base + p] = val & 0x1FFFF;
    }
    __syncthreads();
    if (fit)
        for (int i = tid; i < m; i += 256) csr[base + i] = scsr[i];
    for (int i = tid; i < nn; i += 256)
        offpk[n0 + i] = (unsigned int)((base + loff[i]) | (lcnt[i] << 21));
}

// ---- fused gather+layer: 512 thr, 64 nodes/block, agg stays in LDS --------
// Gather (R6 structure, clamp-to-row-0 batched loads): 8 lanes/node, lane
// owns channels 8l..8l+7, 16 int4 rows in flight; result -> sA (LDS).
// MFMA phase reads B-fragments DIRECTLY from global wpk (fragment order =
// coalesced 16B/lane, 48KB table L2-resident) — no weight LDS arrays.
// LDS 43.5K -> 18.7K (27K head) => 4 blocks/CU (thread-cap), +33% waves.
template <bool FUSE_HEAD>
__global__ void __launch_bounds__(512, 8) fused_gather_layer(
        const ushort_t* __restrict__ featin,
        const unsigned int* __restrict__ offpk, const int* __restrict__ csr,
        const ushort_t* __restrict__ wpk, const float* __restrict__ bias,
        ushort_t* __restrict__ featout,
        const float* __restrict__ Wlin, const float* __restrict__ blin,
        float* __restrict__ out) {
    __shared__ __align__(16) ushort_t sA[64 * MP];
    __shared__ __align__(16) ushort_t sH[64 * MP];
    __shared__ float sbias[HID];
    __shared__ float sWo[FUSE_HEAD ? HID * OUT_CH : 1];
    __shared__ float sbo[FUSE_HEAD ? OUT_CH : 1];
    int tid = threadIdx.x;
    int node0 = blockIdx.x * 64;

    // stage bias + root tile (+ head weights); issued before gather
    if (tid < HID) sbias[tid] = bias[tid];
    if constexpr (FUSE_HEAD) {
        ((int4*)sWo)[tid] = ((const int4*)Wlin)[tid];
        if (tid < OUT_CH) sbo[tid] = blin[tid];
    }
    {   // root: 512 int4 (64 rows x 128B); overread lands in slack
        const int4* gh = (const int4*)(featin + (size_t)node0 * HID);
        int r = tid >> 3, u = tid & 7;
        *(int4*)(sH + r * MP + u * 8) = gh[tid];
    }

    // ---- gather phase (R6 inner loop) ----
    int wv = tid >> 6, ln = tid & 63;
    int g = ln >> 3;          // node sub-group 0..7 within wave
    int l = ln & 7;           // 16B channel slot: channels 8l..8l+7
    int nl = wv * 8 + g;      // node 0..63 within block
    int node = node0 + nl;
    unsigned int v = (node < N_NODES) ? offpk[node] : 0u;
    int off = (int)(v & 0x1FFFFFu);
    int cnt = (int)(v >> 21);
    float a0 = 0.f, a1 = 0.f, a2 = 0.f, a3 = 0.f;
    float a4 = 0.f, a5 = 0.f, a6 = 0.f, a7 = 0.f;
    int gbase = g << 3;
    for (int b = 0; b < cnt; b += 16) {
        int rem = cnt - b;
        int e0 = (l < rem) ? csr[off + b + l] : 0;
        int e1 = (l + 8 < rem) ? csr[off + b + 8 + l] : 0;
        int4 u[16];
#pragma unroll
        for (int j = 0; j < 8; ++j)
            u[j] = ((const int4*)(featin + (size_t)__shfl(e0, gbase + j) * HID))[l];
#pragma unroll
        for (int j = 0; j < 8; ++j)
            u[8 + j] = ((const int4*)(featin + (size_t)__shfl(e1, gbase + j) * HID))[l];
#pragma unroll
        for (int j = 0; j < 16; ++j) {
            if (j >= rem) { u[j].x = 0; u[j].y = 0; u[j].z = 0; u[j].w = 0; }
            a0 += blo(u[j].x); a1 += bhi(u[j].x);
            a2 += blo(u[j].y); a3 += bhi(u[j].y);
            a4 += blo(u[j].z); a5 += bhi(u[j].z);
            a6 += blo(u[j].w); a7 += bhi(u[j].w);
        }
    }
    {   // agg -> LDS: node nl, channels 8l..8l+7
        float inv = 1.f / fmaxf((float)cnt, 1.f);
        int4 w;
        w.x = (int)((unsigned)f2b(a0 * inv) | ((unsigned)f2b(a1 * inv) << 16));
        w.y = (int)((unsigned)f2b(a2 * inv) | ((unsigned)f2b(a3 * inv) << 16));
        w.z = (int)((unsigned)f2b(a4 * inv) | ((unsigned)f2b(a5 * inv) << 16));
        w.w = (int)((unsigned)f2b(a6 * inv) | ((unsigned)f2b(a7 * inv) << 16));
        *(int4*)(sA + nl * MP + l * 8) = w;
    }
    __syncthreads();

    // ---- MFMA phase: wave wv -> m-tile mt, n-tiles {npb, npb+1} ----
    // B-fragments from global wpk: Wl frags = wg[0..511], Wr = wg[512..1023]
    int lane = ln;
    int quad = lane >> 4, col = lane & 15;
    int mt = wv >> 1, npb = (wv & 1) * 2;
    int arow = mt * 16 + col;
    const bf16x8* wg = (const bf16x8*)wpk;
    bf16x8 aA0 = *(const bf16x8*)(sA + arow * MP + quad * 8);
    bf16x8 aA1 = *(const bf16x8*)(sA + arow * MP + 32 + quad * 8);
    bf16x8 aH0 = *(const bf16x8*)(sH + arow * MP + quad * 8);
    bf16x8 aH1 = *(const bf16x8*)(sH + arow * MP + 32 + quad * 8);
    ushort_t hv[2][4];
#pragma unroll
    for (int t = 0; t < 2; ++t) {
        int nt = npb + t;
        bf16x8 bl0 = wg[nt * 128 + lane];
        bf16x8 bl1 = wg[nt * 128 + 64 + lane];
        bf16x8 br0 = wg[512 + nt * 128 + lane];
        bf16x8 br1 = wg[512 + nt * 128 + 64 + lane];
        f32x4 acc = {0.f, 0.f, 0.f, 0.f};
        acc = __builtin_amdgcn_mfma_f32_16x16x32_bf16(aA0, bl0, acc, 0, 0, 0);
        acc = __builtin_amdgcn_mfma_f32_16x16x32_bf16(aA1, bl1, acc, 0, 0, 0);
        acc = __builtin_amdgcn_mfma_f32_16x16x32_bf16(aH0, br0, acc, 0, 0, 0);
        acc = __builtin_amdgcn_mfma_f32_16x16x32_bf16(aH1, br1, acc, 0, 0, 0);
        float bv = sbias[nt * 16 + col];
#pragma unroll
        for (int r = 0; r < 4; ++r) {
            ushort_t hb16 = f2b(fmaxf(acc[r] + bv, 0.f));
            if constexpr (FUSE_HEAD) {
                hv[t][r] = hb16;
            } else {
                int n = node0 + mt * 16 + quad * 4 + r;
                if (n < N_NODES)
                    featout[(size_t)n * HID + nt * 16 + col] = hb16;
            }
        }
    }

    if constexpr (FUSE_HEAD) {
        __syncthreads();   // sA/sH fragment reads done; reuse sA for h tile
#pragma unroll
        for (int t = 0; t < 2; ++t)
#pragma unroll
            for (int r = 0; r < 4; ++r)
                sA[(mt * 16 + quad * 4 + r) * MP + (npb + t) * 16 + col] = hv[t][r];
        __syncthreads();

        int c0 = (tid & 7) << 2;
        int n0 = tid >> 3;           // 1 node per thread
        float acc2[4];
#pragma unroll
        for (int j = 0; j < 4; ++j) acc2[j] = sbo[c0 + j];
#pragma unroll 4
        for (int kk = 0; kk < 32; ++kk) {
            float4 w0 = *(const float4*)&sWo[(2 * kk) * OUT_CH + c0];
            float4 w1 = *(const float4*)&sWo[(2 * kk + 1) * OUT_CH + c0];
            const float* w0p = (const float*)&w0;
            const float* w1p = (const float*)&w1;
            unsigned uh = *(const unsigned*)(sA + n0 * MP + 2 * kk);
            float h0 = blo(uh), h1 = bhi(uh);
#pragma unroll
            for (int j = 0; j < 4; ++j) acc2[j] += h0 * w0p[j] + h1 * w1p[j];
        }
        int n = node0 + n0;
        if (n < N_NODES) {
            float4 o4;
            o4.x = acc2[0]; o4.y = acc2[1]; o4.z = acc2[2]; o4.w = acc2[3];
            *(float4*)(out + (size_t)n * OUT_CH + c0) = o4;
        }
    }
}

extern "C" void kernel_launch(void* const* d_in, const int* in_sizes, int n_in,
                              void* d_out, int out_size, void* d_ws, size_t ws_size,
                              hipStream_t stream) {
    const float* x    = (const float*)d_in[0];
    const int*   ei   = (const int*)d_in[1];
    const float* Wl1  = (const float*)d_in[2];
    const float* Wr1  = (const float*)d_in[3];
    const float* b1   = (const float*)d_in[4];
    const float* Wl2  = (const float*)d_in[5];
    const float* Wr2  = (const float*)d_in[6];
    const float* b2   = (const float*)d_in[7];
    const float* Wl3  = (const float*)d_in[8];
    const float* Wr3  = (const float*)d_in[9];
    const float* b3   = (const float*)d_in[10];
    const float* Wlin = (const float*)d_in[11];
    const float* blin = (const float*)d_in[12];
    float* out = (float*)d_out;

    // workspace layout (4-byte units), ~40 MB; tile overreads land in slack.
    int* ip              = (int*)d_ws;
    unsigned int* offpk  = (unsigned int*)ip;             // 100096
    int* btot            = (int*)(offpk + 100096);        // 256
    int* histG           = btot + 256;                    // NB*P = 200704
    int* csr             = histG + NB * P;                // 1600000
    int* bkt             = csr + N_EDGES;                 // 1600000
    ushort_t* featbA     = (ushort_t*)(bkt + N_EDGES);    // 6.4M bf16 + slack
    ushort_t* featbB     = featbA + 6408192;              // 6.4M bf16 + slack
    ushort_t* wpk        = featbB + 6408192;              // 6*4096 weights

    const int TILE_BLOCKS = (N_NODES + 63) / 64;          // 1563

    // CSR build: convert+hist+wprep, scan, place (coalesced), bucket_fill
    convhist_kernel<<<CONV_BLOCKS + 6, 256, 0, stream>>>(
        x, featbA, ei, histG, Wl1, Wr1, Wl2, Wr2, Wl3, Wr3, wpk);
    scan_kernel<<<NB, 256, 0, stream>>>(histG, btot);
    place_kernel<<<P, 256, 0, stream>>>(ei, histG, btot, bkt);
    bucket_fill_kernel<<<NB, 256, 0, stream>>>(btot, bkt, csr, offpk);

    // layer 1: featbA -> featbB (agg in LDS; ping-pong kills the race)
    fused_gather_layer<false><<<TILE_BLOCKS, 512, 0, stream>>>(
        featbA, offpk, csr, wpk, b1, featbB, nullptr, nullptr, nullptr);

    // layer 2: featbB -> featbA
    fused_gather_layer<false><<<TILE_BLOCKS, 512, 0, stream>>>(
        featbB, offpk, csr, wpk + 8192, b2, featbA, nullptr, nullptr, nullptr);

    // layer 3 + head: featbA -> out
    fused_gather_layer<true><<<TILE_BLOCKS, 512, 0, stream>>>(
        featbA, offpk, csr, wpk + 16384, b3, nullptr, Wlin, blin, out);
}

// Round 13
// 240.815 us; speedup vs baseline: 1.0898x; 1.0898x over previous
//
#include <hip/hip_runtime.h>
#include <hip/hip_bf16.h>

#define N_NODES 100000
#define N_EDGES 1600000
#define HID 64
#define OUT_CH 32

// Deterministic radix partition into dst buckets. Zero global atomics for
// cursors (R5). R1/R2: channel-chunked gather loses (request-rate bound).
// R3: pre-swizzle weights once. R5: head fused into layer3. R6: gather
// MLP-deepening (16 int4 in flight/lane, lane-owned channels) -36 us.
// R7: software grid barriers cost ~100us on MI355X -> never fuse that way.
// R8: block-local gather+layer fusion (agg stays in LDS) -15 us.
// R9: clamp-to-row-0 batched loads beat exec-mask predication on CDNA4.
// R11: place in-LDS counting sort (coalesced bkt writes) -6 us.
// R12 LESSON: gather is at an L2-miss SERVICE-RATE wall (~2 TB/s useful
// bytes in both 3- and 6-block/CU configs); raising occupancy only thrashes
// L2 (FETCH 82->100 MB). Weights stay in LDS; this is the R11 optimum.
#define NB 196           // ceil(100000/512) buckets of 512 consecutive dst nodes
#define P 1024           // partition blocks
#define EPP ((N_EDGES + P - 1) / P)   // 1563 edges per block
#define BKCAP 10240      // LDS csr staging cap (bucket mean 8192, sigma ~90)
#define MP 72            // bf16 tile pitch for MFMA layer (16B-aligned rows)

typedef unsigned short ushort_t;
typedef short bf16x8 __attribute__((ext_vector_type(8)));
typedef float f32x4 __attribute__((ext_vector_type(4)));

// bf16 helpers (RNE)
__device__ __forceinline__ ushort_t f2b(float f) {
    union { float f; unsigned u; } un; un.f = f;
    unsigned r = un.u + 0x7FFF + ((un.u >> 16) & 1);
    return (ushort_t)(r >> 16);
}
__device__ __forceinline__ float blo(unsigned u) {
    union { unsigned u; float f; } un; un.u = u << 16; return un.f;
}
__device__ __forceinline__ float bhi(unsigned u) {
    union { unsigned u; float f; } un; un.u = u & 0xFFFF0000u; return un.f;
}

__device__ __forceinline__ int get_dst(const int* __restrict__ ei, int is64, int e) {
    return is64 ? ((const int2*)ei)[N_EDGES + e].x : ei[N_EDGES + e];
}
__device__ __forceinline__ int get_src(const int* __restrict__ ei, int is64, int e) {
    return is64 ? ((const int2*)ei)[e].x : ei[e];
}

// inline edge-dtype probe: int64 => odd 32-bit words all 0 (first wave)
__device__ __forceinline__ void detect_is64(const int* __restrict__ ei,
                                            int* __restrict__ sflag, int tid) {
    if (tid < 64) {
        int v = ei[2 * tid + 1];
        unsigned long long ball = __ballot(v == 0);
        if (tid == 0) *sflag = (ball == ~0ull) ? 1 : 0;
    }
}

// ---- convert x -> bf16 + bucket histograms (blocks <P) + weight swizzle ---
#define CONV_BLOCKS ((N_NODES * HID / 4) / 256)   // 6250
__global__ void __launch_bounds__(256) convhist_kernel(
        const float* __restrict__ x, ushort_t* __restrict__ xb,
        const int* __restrict__ ei, int* __restrict__ histG,
        const float* __restrict__ W0, const float* __restrict__ W1,
        const float* __restrict__ W2, const float* __restrict__ W3,
        const float* __restrict__ W4, const float* __restrict__ W5,
        ushort_t* __restrict__ wpk) {
    int bid = blockIdx.x;
    if (bid >= CONV_BLOCKS) {        // weight-swizzle blocks
        const float* Ws[6] = {W0, W1, W2, W3, W4, W5};
        int w = bid - CONV_BLOCKS;
        const float* W = Ws[w];
        ushort_t* d = wpk + w * 4096;
        for (int idx = threadIdx.x; idx < 4096; idx += 256) {
            int j = idx & 7;
            int ln = (idx >> 3) & 63;
            int t = idx >> 9;            // nt*2+ks
            int ks = t & 1, nt = t >> 1;
            int k = ks * 32 + (ln >> 4) * 8 + j;
            int n = nt * 16 + (ln & 15);
            d[idx] = f2b(W[k * HID + n]);
        }
        return;
    }
    int i = bid * 256 + threadIdx.x;
    if (i < N_NODES * HID / 4) {
        float4 v = ((const float4*)x)[i];
        ushort4 o;
        o.x = f2b(v.x); o.y = f2b(v.y); o.z = f2b(v.z); o.w = f2b(v.w);
        ((ushort4*)xb)[i] = o;
    }
    if (bid >= P) return;
    __shared__ int sflag;
    __shared__ int lh[NB];
    int tid = threadIdx.x;
    detect_is64(ei, &sflag, tid);
    for (int k = tid; k < NB; k += 256) lh[k] = 0;
    __syncthreads();
    int is64 = sflag;
    int e0 = bid * EPP;
    int e1 = min(e0 + EPP, N_EDGES);
    for (int e = e0 + tid; e < e1; e += 256) {
        int d = get_dst(ei, is64, e);
        atomicAdd(&lh[d >> 9], 1);
    }
    __syncthreads();
    for (int k = tid; k < NB; k += 256) histG[k * P + bid] = lh[k];
}

// ---- per-bucket exclusive scan over P block-counts (4 elems/thread) -------
__global__ void __launch_bounds__(256) scan_kernel(int* __restrict__ histG,
                                                   int* __restrict__ btot) {
    __shared__ int ps[256];
    int b = blockIdx.x;
    int tid = threadIdx.x;
    int base4 = b * P + 4 * tid;
    int v0 = histG[base4], v1 = histG[base4 + 1], v2 = histG[base4 + 2], v3 = histG[base4 + 3];
    int pv = v0 + v1 + v2 + v3;
    ps[tid] = pv;
    __syncthreads();
    for (int d = 1; d < 256; d <<= 1) {
        int t = (tid >= d) ? ps[tid - d] : 0;
        __syncthreads();
        ps[tid] += t;
        __syncthreads();
    }
    int e = ps[tid] - pv;
    histG[base4] = e; e += v0;
    histG[base4 + 1] = e; e += v1;
    histG[base4 + 2] = e; e += v2;
    histG[base4 + 3] = e;
    if (tid == 255) btot[b] = ps[255];
}

// ---- place v2: in-LDS counting sort, coalesced bkt writes -----------------
__global__ void __launch_bounds__(256) place_kernel(
        const int* __restrict__ ei, const int* __restrict__ histG,
        const int* __restrict__ btot, int* __restrict__ bkt) {
    __shared__ int ss[256];
    __shared__ int sflag;
    __shared__ int gb0[NB];      // bucket global base + my scanned offset
    __shared__ int lcnt[NB];
    __shared__ int lrun[256];    // scan workspace
    __shared__ int gbase[NB];    // gb0[k] - excl[k]
    __shared__ int lcur[NB];
    __shared__ int valbuf[EPP];
    __shared__ unsigned char kbuf[EPP];
    __shared__ int sortv[EPP];
    __shared__ int sorta[EPP];
    int tid = threadIdx.x;
    detect_is64(ei, &sflag, tid);
    int v = (tid < NB) ? btot[tid] : 0;
    ss[tid] = v;
    __syncthreads();
    for (int d = 1; d < 256; d <<= 1) {
        int t = (tid >= d) ? ss[tid - d] : 0;
        __syncthreads();
        ss[tid] += t;
        __syncthreads();
    }
    if (tid < NB) gb0[tid] = (ss[tid] - v) + histG[tid * P + blockIdx.x];
    for (int k = tid; k < NB; k += 256) lcnt[k] = 0;
    __syncthreads();
    int is64 = sflag;
    int e0 = blockIdx.x * EPP;
    int e1 = min(e0 + EPP, N_EDGES);
    int m = e1 - e0;
    for (int i = tid; i < m; i += 256) {
        int e = e0 + i;
        int s = get_src(ei, is64, e);
        int d = get_dst(ei, is64, e);
        valbuf[i] = ((d & 511) << 17) | s;
        int k = d >> 9;
        kbuf[i] = (unsigned char)k;
        atomicAdd(&lcnt[k], 1);
    }
    __syncthreads();
    int c = (tid < NB) ? lcnt[tid] : 0;
    lrun[tid] = c;
    __syncthreads();
    for (int d = 1; d < 256; d <<= 1) {
        int t = (tid >= d) ? lrun[tid - d] : 0;
        __syncthreads();
        lrun[tid] += t;
        __syncthreads();
    }
    if (tid < NB) {
        int excl = lrun[tid] - c;
        gbase[tid] = gb0[tid] - excl;
        lcur[tid] = excl;
    }
    __syncthreads();
    for (int i = tid; i < m; i += 256) {
        int k = kbuf[i];
        int p = atomicAdd(&lcur[k], 1);
        sortv[p] = valbuf[i];
        sorta[p] = gbase[k];
    }
    __syncthreads();
    for (int i = tid; i < m; i += 256)
        bkt[sorta[i] + i] = sortv[i];
}

// ---- per-bucket csr build in LDS + packed off|deg -------------------------
__global__ void __launch_bounds__(256) bucket_fill_kernel(
        const int* __restrict__ btot, const int* __restrict__ bkt,
        int* __restrict__ csr, unsigned int* __restrict__ offpk) {
    __shared__ int lcnt[512];
    __shared__ int loff[512];
    __shared__ int lcur[512];
    __shared__ int ps[256];
    __shared__ int scsr[BKCAP];
    __shared__ int sbase;
    int b = blockIdx.x;
    int tid = threadIdx.x;
    int m = btot[b];
    int vb = (tid < NB) ? btot[tid] : 0;
    ps[tid] = vb;
    __syncthreads();
    for (int d = 1; d < 256; d <<= 1) {
        int t = (tid >= d) ? ps[tid - d] : 0;
        __syncthreads();
        ps[tid] += t;
        __syncthreads();
    }
    if (tid == b) sbase = ps[tid] - vb;   // exclusive prefix at b
    __syncthreads();
    int base = sbase;
    int n0 = b << 9;
    int nn = min(512, N_NODES - n0);

    lcnt[tid] = 0;
    lcnt[tid + 256] = 0;
    __syncthreads();
    for (int i = tid; i < m; i += 256) atomicAdd(&lcnt[bkt[base + i] >> 17], 1);
    __syncthreads();
    int a0 = lcnt[2 * tid], a1 = lcnt[2 * tid + 1];
    int pv = a0 + a1;
    ps[tid] = pv;
    __syncthreads();
    for (int d = 1; d < 256; d <<= 1) {
        int t = (tid >= d) ? ps[tid - d] : 0;
        __syncthreads();
        ps[tid] += t;
        __syncthreads();
    }
    int excl = ps[tid] - pv;
    loff[2 * tid] = excl;
    loff[2 * tid + 1] = excl + a0;
    lcur[2 * tid] = excl;
    lcur[2 * tid + 1] = excl + a0;
    __syncthreads();
    bool fit = (m <= BKCAP);
    for (int i = tid; i < m; i += 256) {
        int val = bkt[base + i];
        int dl = val >> 17;
        int p = atomicAdd(&lcur[dl], 1);
        if (fit) scsr[p] = val & 0x1FFFF;
        else csr[base + p] = val & 0x1FFFF;
    }
    __syncthreads();
    if (fit)
        for (int i = tid; i < m; i += 256) csr[base + i] = scsr[i];
    for (int i = tid; i < nn; i += 256)
        offpk[n0 + i] = (unsigned int)((base + loff[i]) | (lcnt[i] << 21));
}

// ---- fused gather+layer: 512 thr, 64 nodes/block, agg stays in LDS --------
// Gather (R6 structure, clamp-to-row-0 batched loads — R9 lesson): 8
// lanes/node, lane owns channels 8l..8l+7, 16 int4 rows in flight; result
// written to sA (LDS), NOT global. Then one barrier and the MFMA layer
// runs in-block: 8 waves, wave wv owns m-tile wv>>1, n-tiles {2(wv&1)..+1}.
template <bool FUSE_HEAD>
__global__ void __launch_bounds__(512, 4) fused_gather_layer(
        const ushort_t* __restrict__ featin,
        const unsigned int* __restrict__ offpk, const int* __restrict__ csr,
        const ushort_t* __restrict__ wpk, const float* __restrict__ bias,
        ushort_t* __restrict__ featout,
        const float* __restrict__ Wlin, const float* __restrict__ blin,
        float* __restrict__ out) {
    __shared__ __align__(16) ushort_t sWlF[4096];
    __shared__ __align__(16) ushort_t sWrF[4096];
    __shared__ __align__(16) ushort_t sA[64 * MP];
    __shared__ __align__(16) ushort_t sH[64 * MP];
    __shared__ float sbias[HID];
    __shared__ float sWo[FUSE_HEAD ? HID * OUT_CH : 1];
    __shared__ float sbo[FUSE_HEAD ? OUT_CH : 1];
    int tid = threadIdx.x;
    int node0 = blockIdx.x * 64;

    // stage weights + bias + root tile (coalesced; issued before gather)
    ((int4*)sWlF)[tid] = ((const int4*)wpk)[tid];
    ((int4*)sWrF)[tid] = ((const int4*)wpk)[512 + tid];
    if (tid < HID) sbias[tid] = bias[tid];
    if constexpr (FUSE_HEAD) {
        ((int4*)sWo)[tid] = ((const int4*)Wlin)[tid];
        if (tid < OUT_CH) sbo[tid] = blin[tid];
    }
    {   // root: 512 int4 (64 rows x 128B); overread lands in slack
        const int4* gh = (const int4*)(featin + (size_t)node0 * HID);
        int r = tid >> 3, u = tid & 7;
        *(int4*)(sH + r * MP + u * 8) = gh[tid];
    }

    // ---- gather phase (R6 inner loop) ----
    int wv = tid >> 6, ln = tid & 63;
    int g = ln >> 3;          // node sub-group 0..7 within wave
    int l = ln & 7;           // 16B channel slot: channels 8l..8l+7
    int nl = wv * 8 + g;      // node 0..63 within block
    int node = node0 + nl;
    unsigned int v = (node < N_NODES) ? offpk[node] : 0u;
    int off = (int)(v & 0x1FFFFFu);
    int cnt = (int)(v >> 21);
    float a0 = 0.f, a1 = 0.f, a2 = 0.f, a3 = 0.f;
    float a4 = 0.f, a5 = 0.f, a6 = 0.f, a7 = 0.f;
    int gbase = g << 3;
    for (int b = 0; b < cnt; b += 16) {
        int rem = cnt - b;
        int e0 = (l < rem) ? csr[off + b + l] : 0;
        int e1 = (l + 8 < rem) ? csr[off + b + 8 + l] : 0;
        int4 u[16];
#pragma unroll
        for (int j = 0; j < 8; ++j)
            u[j] = ((const int4*)(featin + (size_t)__shfl(e0, gbase + j) * HID))[l];
#pragma unroll
        for (int j = 0; j < 8; ++j)
            u[8 + j] = ((const int4*)(featin + (size_t)__shfl(e1, gbase + j) * HID))[l];
#pragma unroll
        for (int j = 0; j < 16; ++j) {
            if (j >= rem) { u[j].x = 0; u[j].y = 0; u[j].z = 0; u[j].w = 0; }
            a0 += blo(u[j].x); a1 += bhi(u[j].x);
            a2 += blo(u[j].y); a3 += bhi(u[j].y);
            a4 += blo(u[j].z); a5 += bhi(u[j].z);
            a6 += blo(u[j].w); a7 += bhi(u[j].w);
        }
    }
    {   // agg -> LDS (was global aggb): node nl, channels 8l..8l+7
        float inv = 1.f / fmaxf((float)cnt, 1.f);
        int4 w;
        w.x = (int)((unsigned)f2b(a0 * inv) | ((unsigned)f2b(a1 * inv) << 16));
        w.y = (int)((unsigned)f2b(a2 * inv) | ((unsigned)f2b(a3 * inv) << 16));
        w.z = (int)((unsigned)f2b(a4 * inv) | ((unsigned)f2b(a5 * inv) << 16));
        w.w = (int)((unsigned)f2b(a6 * inv) | ((unsigned)f2b(a7 * inv) << 16));
        *(int4*)(sA + nl * MP + l * 8) = w;
    }
    __syncthreads();

    // ---- MFMA phase: wave wv -> m-tile mt, n-tiles {npb, npb+1} ----
    int lane = ln;
    int quad = lane >> 4, col = lane & 15;
    int mt = wv >> 1, npb = (wv & 1) * 2;
    int arow = mt * 16 + col;
    bf16x8 aA0 = *(const bf16x8*)(sA + arow * MP + quad * 8);
    bf16x8 aA1 = *(const bf16x8*)(sA + arow * MP + 32 + quad * 8);
    bf16x8 aH0 = *(const bf16x8*)(sH + arow * MP + quad * 8);
    bf16x8 aH1 = *(const bf16x8*)(sH + arow * MP + 32 + quad * 8);
    ushort_t hv[2][4];
#pragma unroll
    for (int t = 0; t < 2; ++t) {
        int nt = npb + t;
        f32x4 acc = {0.f, 0.f, 0.f, 0.f};
        const bf16x8* bl = (const bf16x8*)(sWlF + nt * 1024);
        const bf16x8* br = (const bf16x8*)(sWrF + nt * 1024);
        acc = __builtin_amdgcn_mfma_f32_16x16x32_bf16(aA0, bl[lane], acc, 0, 0, 0);
        acc = __builtin_amdgcn_mfma_f32_16x16x32_bf16(aA1, bl[64 + lane], acc, 0, 0, 0);
        acc = __builtin_amdgcn_mfma_f32_16x16x32_bf16(aH0, br[lane], acc, 0, 0, 0);
        acc = __builtin_amdgcn_mfma_f32_16x16x32_bf16(aH1, br[64 + lane], acc, 0, 0, 0);
        float bv = sbias[nt * 16 + col];
#pragma unroll
        for (int r = 0; r < 4; ++r) {
            ushort_t hb16 = f2b(fmaxf(acc[r] + bv, 0.f));
            if constexpr (FUSE_HEAD) {
                hv[t][r] = hb16;
            } else {
                int n = node0 + mt * 16 + quad * 4 + r;
                if (n < N_NODES)
                    featout[(size_t)n * HID + nt * 16 + col] = hb16;
            }
        }
    }

    if constexpr (FUSE_HEAD) {
        __syncthreads();   // sA/sH fragment reads done; reuse sA for h tile
#pragma unroll
        for (int t = 0; t < 2; ++t)
#pragma unroll
            for (int r = 0; r < 4; ++r)
                sA[(mt * 16 + quad * 4 + r) * MP + (npb + t) * 16 + col] = hv[t][r];
        __syncthreads();

        int c0 = (tid & 7) << 2;
        int n0 = tid >> 3;           // 1 node per thread
        float acc2[4];
#pragma unroll
        for (int j = 0; j < 4; ++j) acc2[j] = sbo[c0 + j];
#pragma unroll 4
        for (int kk = 0; kk < 32; ++kk) {
            float4 w0 = *(const float4*)&sWo[(2 * kk) * OUT_CH + c0];
            float4 w1 = *(const float4*)&sWo[(2 * kk + 1) * OUT_CH + c0];
            const float* w0p = (const float*)&w0;
            const float* w1p = (const float*)&w1;
            unsigned uh = *(const unsigned*)(sA + n0 * MP + 2 * kk);
            float h0 = blo(uh), h1 = bhi(uh);
#pragma unroll
            for (int j = 0; j < 4; ++j) acc2[j] += h0 * w0p[j] + h1 * w1p[j];
        }
        int n = node0 + n0;
        if (n < N_NODES) {
            float4 o4;
            o4.x = acc2[0]; o4.y = acc2[1]; o4.z = acc2[2]; o4.w = acc2[3];
            *(float4*)(out + (size_t)n * OUT_CH + c0) = o4;
        }
    }
}

extern "C" void kernel_launch(void* const* d_in, const int* in_sizes, int n_in,
                              void* d_out, int out_size, void* d_ws, size_t ws_size,
                              hipStream_t stream) {
    const float* x    = (const float*)d_in[0];
    const int*   ei   = (const int*)d_in[1];
    const float* Wl1  = (const float*)d_in[2];
    const float* Wr1  = (const float*)d_in[3];
    const float* b1   = (const float*)d_in[4];
    const float* Wl2  = (const float*)d_in[5];
    const float* Wr2  = (const float*)d_in[6];
    const float* b2   = (const float*)d_in[7];
    const float* Wl3  = (const float*)d_in[8];
    const float* Wr3  = (const float*)d_in[9];
    const float* b3   = (const float*)d_in[10];
    const float* Wlin = (const float*)d_in[11];
    const float* blin = (const float*)d_in[12];
    float* out = (float*)d_out;

    // workspace layout (4-byte units), ~40 MB; tile overreads land in slack.
    int* ip              = (int*)d_ws;
    unsigned int* offpk  = (unsigned int*)ip;             // 100096
    int* btot            = (int*)(offpk + 100096);        // 256
    int* histG           = btot + 256;                    // NB*P = 200704
    int* csr             = histG + NB * P;                // 1600000
    int* bkt             = csr + N_EDGES;                 // 1600000
    ushort_t* featbA     = (ushort_t*)(bkt + N_EDGES);    // 6.4M bf16 + slack
    ushort_t* featbB     = featbA + 6408192;              // 6.4M bf16 + slack
    ushort_t* wpk        = featbB + 6408192;              // 6*4096 weights

    const int TILE_BLOCKS = (N_NODES + 63) / 64;          // 1563

    // CSR build: convert+hist+wprep, scan, place (coalesced), bucket_fill
    convhist_kernel<<<CONV_BLOCKS + 6, 256, 0, stream>>>(
        x, featbA, ei, histG, Wl1, Wr1, Wl2, Wr2, Wl3, Wr3, wpk);
    scan_kernel<<<NB, 256, 0, stream>>>(histG, btot);
    place_kernel<<<P, 256, 0, stream>>>(ei, histG, btot, bkt);
    bucket_fill_kernel<<<NB, 256, 0, stream>>>(btot, bkt, csr, offpk);

    // layer 1: featbA -> featbB (agg in LDS; ping-pong kills the race)
    fused_gather_layer<false><<<TILE_BLOCKS, 512, 0, stream>>>(
        featbA, offpk, csr, wpk, b1, featbB, nullptr, nullptr, nullptr);

    // layer 2: featbB -> featbA
    fused_gather_layer<false><<<TILE_BLOCKS, 512, 0, stream>>>(
        featbB, offpk, csr, wpk + 8192, b2, featbA, nullptr, nullptr, nullptr);

    // layer 3 + head: featbA -> out
    fused_gather_layer<true><<<TILE_BLOCKS, 512, 0, stream>>>(
        featbA, offpk, csr, wpk + 16384, b3, nullptr, Wlin, blin, out);
}